// Round 19
// baseline (204.299 us; speedup 1.0000x reference)
//
#include <hip/hip_runtime.h>

typedef unsigned short u16;
typedef unsigned int   u32;
typedef __attribute__((ext_vector_type(8)))  short short8;   // 8 x bf16
typedef __attribute__((ext_vector_type(4)))  float floatx4;
typedef __attribute__((ext_vector_type(16))) float floatx16;

#define CNEG  (-1.4426950408889634e9f)   // -1e9 * log2(e)  (exp2 domain)
#define QSCL  (0.12753129020334545f)     // (1/sqrt(128)) * log2(e)
#define NEGF  (-1000000000.0f)           // fallback kernel (exp domain)
#define DEFER_THR 8.0f

__device__ __forceinline__ u16 f2bf(float x) {            // f32 -> bf16 RNE
  u32 u = __builtin_bit_cast(u32, x);
  u += 0x7fffu + ((u >> 16) & 1u);
  return (u16)(u >> 16);
}
__device__ __forceinline__ u32 cvtpk(float lo, float hi) { // 2xf32 -> packed bf16
  u32 r;
  asm("v_cvt_pk_bf16_f32 %0, %1, %2" : "=v"(r) : "v"(lo), "v"(hi));
  return r;
}

// fallback-kernel swizzles
__device__ __forceinline__ int swzK(int r, int c)  { return r * 128 + (c ^ ((r & 7) << 3)); }
__device__ __forceinline__ int svb(int d)          { return ((d & 7) ^ ((d >> 2) & 7)) << 3; }
__device__ __forceinline__ int swzV(int d, int kv) { return d * 64 + (kv ^ svb(d)); }
// swap bits 2<->3 of a 5-bit index (sigma for 32x32 C/D -> PV-B alignment)
__device__ __forceinline__ int swap23(int x) {
  return (x & ~0xC) | ((x & 4) << 1) | ((x & 8) >> 1);
}

__device__ __forceinline__ void gld16(const void* g, void* l) {
  __builtin_amdgcn_global_load_lds(
      (const __attribute__((address_space(1))) u32*)g,
      (__attribute__((address_space(3))) u32*)l, 16, 0, 0);
}

constexpr int Hh = 16, Ss = 2048, Dd = 128;
constexpr int KVBLK = 64;
constexpr int NT = Ss / KVBLK;            // 32 kv tiles
constexpr int TILE = KVBLK * Dd;          // 8192 elements = 16 KB per bf16 tile
constexpr int NELEM = 4 * Hh * Ss * Dd;   // 16777216 per tensor
constexpr int MASKN = 4 * Ss;             // 8192 mask entries

// ---------------- prep: K/V -> bf16 fragment-linear (32x32); mask -> CNEG-adds; masked-V partials ----------------
__global__ __launch_bounds__(256) void prep_kv(const float* __restrict__ K,
                                               const float* __restrict__ V,
                                               const int* __restrict__ MSK,
                                               u16* __restrict__ Kp, u16* __restrict__ Vp,
                                               float* __restrict__ Mg,
                                               float* __restrict__ Sp) {
  __shared__ u16 Vl[KVBLK * 132];
  const int blk = blockIdx.x, tid = threadIdx.x;   // blk = bh*32 + t
  const float* kg = K + (size_t)blk * TILE;
  const float* vg = V + (size_t)blk * TILE;
  u16* kp = Kp + (size_t)blk * TILE;
  u16* vp = Vp + (size_t)blk * TILE;

  if (blk < MASKN / 256) {                         // mask -> exp2-domain additive floats
    int i = blk * 256 + tid;
    Mg[i] = MSK[i] ? 0.0f : CNEG;
  }

  // K fragments: frag f = kvb*8+s; lane ln holds Kslot[kvb*32+(ln&31)][s*16+(ln>>5)*8+i],
  // slot row -> source kv = kvb*32 + swap23(ln&31)
  #pragma unroll
  for (int it = 0; it < 4; ++it) {
    int ch = tid + it * 256;             // chunk = f*64 + ln, 0..1023
    int f = ch >> 6, ln = ch & 63;
    int kvb = f >> 3, s = f & 7;
    int kvs = kvb * 32 + swap23(ln & 31);          // source kv row
    int d0 = s * 16 + (ln >> 5) * 8;
    const float* src = kg + kvs * 128 + d0;
    float4 a = *(const float4*)src, bq = *(const float4*)(src + 4);
    union { short8 v; u16 h[8]; } u;
    u.h[0] = f2bf(a.x);  u.h[1] = f2bf(a.y);  u.h[2] = f2bf(a.z);  u.h[3] = f2bf(a.w);
    u.h[4] = f2bf(bq.x); u.h[5] = f2bf(bq.y); u.h[6] = f2bf(bq.z); u.h[7] = f2bf(bq.w);
    *(short8*)(kp + ch * 8) = u.v;
  }
  // V: coalesced read -> LDS bf16 [kv][d]
  #pragma unroll
  for (int it = 0; it < 8; ++it) {
    int e = (tid + it * 256) * 4;
    int r = e >> 7, c = e & 127;
    float4 a = *(const float4*)(vg + e);
    uint2 w;
    w.x = (u32)f2bf(a.x) | ((u32)f2bf(a.y) << 16);
    w.y = (u32)f2bf(a.z) | ((u32)f2bf(a.w) << 16);
    *(uint2*)&Vl[r * 132 + c] = w;
  }
  __syncthreads();
  // V fragments: frag f = dt*4+s; lane ln holds V^T[dt*32+(ln&31)][s*16+(ln>>5)*8+i]
  #pragma unroll
  for (int it = 0; it < 4; ++it) {
    int ch = tid + it * 256;
    int f = ch >> 6, ln = ch & 63;
    int dt = f >> 2, s = f & 3;
    int d = dt * 32 + (ln & 31);
    int kv0 = s * 16 + (ln >> 5) * 8;
    union { short8 v; u16 h[8]; } u;
    #pragma unroll
    for (int i = 0; i < 8; ++i) u.h[i] = Vl[(kv0 + i) * 132 + d];
    *(short8*)(vp + ch * 8) = u.v;
  }

  // masked V column partial sums (f32, for the quirk fixup)
  {
    const int d = tid & 127, hf = tid >> 7;
    const int bb = blk >> 9;
    const int j0 = (blk & 31) * 64 + hf * 32;
    float acc = 0.0f;
    #pragma unroll 4
    for (int jj = 0; jj < 32; ++jj) {
      const float mfv = MSK[bb * Ss + j0 + jj] ? 1.0f : 0.0f;
      acc = fmaf(mfv, vg[(hf * 32 + jj) * 128 + d], acc);
    }
    __syncthreads();
    float* sred = (float*)Vl;
    if (hf) sred[d] = acc;
    __syncthreads();
    if (!hf) Sp[(size_t)blk * 128 + d] = acc + sred[d];
  }
}

// ---------------- F1[b] = first unmasked index (Ss if none); M1[b] = #unmasked ----------------
__global__ __launch_bounds__(256) void mask_scan(const int* __restrict__ MSK,
                                                 int* __restrict__ F1M1) {
  __shared__ int sf[4], sc[4];
  const int b = blockIdx.x, tid = threadIdx.x, lane = tid & 63, wid = tid >> 6;
  int first = Ss, cnt = 0;
  for (int j = tid; j < Ss; j += 256)
    if (MSK[b * Ss + j]) { if (j < first) first = j; cnt++; }
  #pragma unroll
  for (int off = 1; off < 64; off <<= 1) {
    first = min(first, __shfl_xor(first, off, 64));
    cnt  += __shfl_xor(cnt, off, 64);
  }
  if (lane == 0) { sf[wid] = first; sc[wid] = cnt; }
  __syncthreads();
  if (tid == 0) {
    int f = min(min(sf[0], sf[1]), min(sf[2], sf[3]));
    int c = sc[0] + sc[1] + sc[2] + sc[3];
    F1M1[b] = f; F1M1[4 + b] = c;
  }
}

// ---------------- fixup for quirk rows (all-masked visible prefix): uniform average ----------------
__global__ __launch_bounds__(128) void fixup(const float* __restrict__ V,
                                             const float* __restrict__ Sp,
                                             const int* __restrict__ F1M1,
                                             float* __restrict__ O) {
  const int bh = blockIdx.x, b = bh >> 4, d = threadIdx.x;
  const int f1 = F1M1[b];
  if (f1 == 0) return;
  const int m1 = F1M1[4 + b];
  float s1v = 0.0f;
  #pragma unroll
  for (int t = 0; t < NT; ++t) s1v += Sp[((size_t)bh * NT + t) * 128 + d];
  float pref = 0.0f;
  for (int i = 0; i < f1; ++i) {
    pref += V[((size_t)bh * Ss + i) * Dd + d];
    O[((size_t)bh * Ss + i) * Dd + d] = (pref + s1v) / (float)(i + 1 + m1);
  }
}

// ---------------- main: 4 waves x 32 q-rows, T15 pipeline: softmax(t) | barrier | QK(t+1)+PV(t) ----------------
// Scores held across tiles (two score sets, named -> static indexing). K+V double-buffered (64KB).
// Per tile: softmax(t) pre-barrier (drain covered by full tile of work); after barrier mask loads
// are issued BEFORE stages (FIFO: C-init waits vmcnt(8), stages stay in flight); then 32 contiguous
// MFMAs (QK(t+1) + PV(t)) with no VALU gap on the matrix pipe.
__global__ __launch_bounds__(256, 2) void attn_fwd(const float* __restrict__ Q,
                                                   const u16* __restrict__ Kp,
                                                   const u16* __restrict__ Vp,
                                                   const float* __restrict__ Mg,
                                                   float* __restrict__ O) {
  __shared__ u16 Kl[2][TILE];              // 32 KB
  __shared__ u16 Vt[2][TILE];              // 32 KB

  const int tid = threadIdx.x, lane = tid & 63, wid = tid >> 6;
  const int l31 = lane & 31, h = lane >> 5;
  const int id = blockIdx.x;                       // 1024 blocks, bijective XCD swizzle
  const int wg = (id & 7) * 128 + (id >> 3);
  const int bh = wg >> 4, b = bh >> 4;
  const int qt = 15 - (wg & 15);                   // longest strips first
  const int qbase = qt * 128;
  const int nT = 2 * qt + 2;                       // causal kv tiles (always even)
  const int qi = qbase + wid * 32 + l31;           // this lane's single q-row

  const size_t tb = (size_t)bh * NT;
  auto stageK = [&](int buf, int t) {      // 16KB: 4 gld16/thread
    const char* gk = (const char*)(Kp + (tb + t) * TILE) + wid * 1024 + lane * 16;
    char* lk = (char*)&Kl[buf][0] + wid * 1024;
    #pragma unroll
    for (int i = 0; i < 4; ++i) gld16(gk + i * 4096, lk + i * 4096);
  };
  auto stageV = [&](int buf, int t) {      // 16KB: 4 gld16/thread
    const char* gv = (const char*)(Vp + (tb + t) * TILE) + wid * 1024 + lane * 16;
    char* lv = (char*)&Vt[buf][0] + wid * 1024;
    #pragma unroll
    for (int i = 0; i < 4; ++i) gld16(gv + i * 4096, lv + i * 4096);
  };

  // Q fragments (B operand): col=q=l31, d = s*16 + h*8 + i
  const float* qgp = Q + ((size_t)bh * Ss + qi) * Dd + h * 8;
  short8 qf[8];
  #pragma unroll
  for (int s = 0; s < 8; ++s) {
    float4 x0 = *(const float4*)(qgp + s * 16);
    float4 x1 = *(const float4*)(qgp + s * 16 + 4);
    union { short8 v; u16 hh[8]; } u;
    u.hh[0] = f2bf(x0.x * QSCL); u.hh[1] = f2bf(x0.y * QSCL);
    u.hh[2] = f2bf(x0.z * QSCL); u.hh[3] = f2bf(x0.w * QSCL);
    u.hh[4] = f2bf(x1.x * QSCL); u.hh[5] = f2bf(x1.y * QSCL);
    u.hh[6] = f2bf(x1.z * QSCL); u.hh[7] = f2bf(x1.w * QSCL);
    qf[s] = u.v;
  }

  float m_run = -3.0e38f, l_part = 0.0f;
  floatx16 oacc[4];
  #pragma unroll
  for (int dt = 0; dt < 4; ++dt)
    #pragma unroll
    for (int r = 0; r < 16; ++r) oacc[dt][r] = 0.0f;

  floatx16 sA0, sA1, sB0, sB1;

  // C-init + QK for tile t into (d0,d1) from K buffer kbuf; masks loaded by caller into mr[8]
  auto qk_tile = [&](floatx16& d0, floatx16& d1, int t, int kbuf,
                     const float4& a0, const float4& a1, const float4& a2, const float4& a3,
                     const float4& a4, const float4& a5, const float4& a6, const float4& a7) {
    d0[0]=a0.x;  d0[1]=a0.y;  d0[2]=a0.z;  d0[3]=a0.w;
    d0[4]=a1.x;  d0[5]=a1.y;  d0[6]=a1.z;  d0[7]=a1.w;
    d0[8]=a2.x;  d0[9]=a2.y;  d0[10]=a2.z; d0[11]=a2.w;
    d0[12]=a3.x; d0[13]=a3.y; d0[14]=a3.z; d0[15]=a3.w;
    d1[0]=a4.x;  d1[1]=a4.y;  d1[2]=a4.z;  d1[3]=a4.w;
    d1[4]=a5.x;  d1[5]=a5.y;  d1[6]=a5.z;  d1[7]=a5.w;
    d1[8]=a6.x;  d1[9]=a6.y;  d1[10]=a6.z; d1[11]=a6.w;
    d1[12]=a7.x; d1[13]=a7.y; d1[14]=a7.z; d1[15]=a7.w;
    const int kvbase = t * KVBLK;
    if (kvbase + KVBLK - 1 >= qbase + wid * 32) {       // diagonal/future for this wave
      #pragma unroll
      for (int r = 0; r < 16; ++r) {
        const int j0 = kvbase + ((r >> 3) << 4) + h * 8 + (r & 7);
        if (j0 > qi)      d0[r] += CNEG;
        if (j0 + 32 > qi) d1[r] += CNEG;
      }
    }
    const u16* kb = &Kl[kbuf][lane * 8];
    __builtin_amdgcn_s_setprio(1);
    #pragma unroll
    for (int s = 0; s < 8; ++s) {
      short8 k0 = *(const short8*)&kb[s * 512];
      short8 k1 = *(const short8*)&kb[(8 + s) * 512];
      d0 = __builtin_amdgcn_mfma_f32_32x32x16_bf16(k0, qf[s], d0, 0, 0, 0);
      d1 = __builtin_amdgcn_mfma_f32_32x32x16_bf16(k1, qf[s], d1, 0, 0, 0);
    }
    __builtin_amdgcn_s_setprio(0);
  };

  // one pipeline phase: softmax(cur=tile t) pre-barrier; post-barrier: masks(t+1), stages,
  // QK(t+1)->nxt, PV(t) with pu
  auto phase = [&](floatx16& c0, floatx16& c1, floatx16& n0, floatx16& n1, int t) {
    // --- softmax on (c0,c1) ---
    float mx8[8];
    #pragma unroll
    for (int r = 0; r < 8; ++r)
      mx8[r] = fmaxf(fmaxf(c0[r], c0[r + 8]), fmaxf(c1[r], c1[r + 8]));
    float mx4[4];
    #pragma unroll
    for (int r = 0; r < 4; ++r) mx4[r] = fmaxf(mx8[r], mx8[r + 4]);
    float pmax = fmaxf(fmaxf(mx4[0], mx4[1]), fmaxf(mx4[2], mx4[3]));

    float mn = m_run;
    if (!__all(pmax <= m_run + DEFER_THR)) {
      pmax = fmaxf(pmax, __shfl_xor(pmax, 32, 64));
      mn = fmaxf(m_run, pmax);
      const float alpha = exp2f(m_run - mn);
      m_run = mn;
      l_part *= alpha;
      #pragma unroll
      for (int dt = 0; dt < 4; ++dt)
        #pragma unroll
        for (int r = 0; r < 16; ++r) oacc[dt][r] *= alpha;
    }
    #pragma unroll
    for (int r = 0; r < 16; ++r) {
      c0[r] = exp2f(c0[r] - mn);
      c1[r] = exp2f(c1[r] - mn);
    }
    union { short8 v; u32 w[4]; } pu[4];
    #pragma unroll
    for (int j = 0; j < 4; ++j) {
      pu[0].w[j] = cvtpk(c0[2 * j],     c0[2 * j + 1]);
      pu[1].w[j] = cvtpk(c0[8 + 2 * j], c0[8 + 2 * j + 1]);
      pu[2].w[j] = cvtpk(c1[2 * j],     c1[2 * j + 1]);
      pu[3].w[j] = cvtpk(c1[8 + 2 * j], c1[8 + 2 * j + 1]);
    }
    {
      float t8[8];
      #pragma unroll
      for (int r = 0; r < 8; ++r)
        t8[r] = (c0[r] + c0[r + 8]) + (c1[r] + c1[r + 8]);
      float t4a = t8[0] + t8[4], t4b = t8[1] + t8[5];
      float t4c = t8[2] + t8[6], t4d = t8[3] + t8[7];
      l_part += (t4a + t4b) + (t4c + t4d);
    }

    __syncthreads();                       // V(t), K(t+1) staged a full tile ago: resident

    const bool hasNext = (t + 1 < nT);
    if (hasNext) {
      // masks(t+1) FIRST (oldest in FIFO), then stages -> C-init waits vmcnt(8)
      const float* mrow = Mg + b * Ss + (t + 1) * KVBLK + h * 8;
      float4 a0 = *(const float4*)(mrow);
      float4 a1 = *(const float4*)(mrow + 4);
      float4 a2 = *(const float4*)(mrow + 16);
      float4 a3 = *(const float4*)(mrow + 20);
      float4 a4 = *(const float4*)(mrow + 32);
      float4 a5 = *(const float4*)(mrow + 36);
      float4 a6 = *(const float4*)(mrow + 48);
      float4 a7 = *(const float4*)(mrow + 52);
      stageV((t + 1) & 1, t + 1);
      if (t + 2 < nT) stageK(t & 1, t + 2);
      // QK(t+1) (mask C-init consumes vmcnt(8); stages stay in flight)
      qk_tile(n0, n1, t + 1, (t + 1) & 1, a0, a1, a2, a3, a4, a5, a6, a7);
    }

    // --- PV(t) from Vt[t&1] with pu (contiguous with QK's MFMAs on the matrix pipe) ---
    const u16* vb = &Vt[t & 1][lane * 8];
    __builtin_amdgcn_s_setprio(1);
    #pragma unroll
    for (int ss = 0; ss < 4; ++ss) {
      #pragma unroll
      for (int dt = 0; dt < 4; ++dt) {
        short8 vf = *(const short8*)&vb[(dt * 4 + ss) * 512];
        oacc[dt] = __builtin_amdgcn_mfma_f32_32x32x16_bf16(vf, pu[ss].v, oacc[dt], 0, 0, 0);
      }
    }
    __builtin_amdgcn_s_setprio(0);
  };

  // --- prologue: K(0) resident; V(0)+K(1) in flight; QK(0) -> sA ---
  stageK(0, 0);
  __syncthreads();
  {
    const float* mrow = Mg + b * Ss + h * 8;
    float4 a0 = *(const float4*)(mrow);
    float4 a1 = *(const float4*)(mrow + 4);
    float4 a2 = *(const float4*)(mrow + 16);
    float4 a3 = *(const float4*)(mrow + 20);
    float4 a4 = *(const float4*)(mrow + 32);
    float4 a5 = *(const float4*)(mrow + 36);
    float4 a6 = *(const float4*)(mrow + 48);
    float4 a7 = *(const float4*)(mrow + 52);
    stageV(0, 0);
    if (nT > 1) stageK(1, 1);
    qk_tile(sA0, sA1, 0, 0, a0, a1, a2, a3, a4, a5, a6, a7);
  }

  // --- main loop: pairs of phases with statically-named score sets (rule #20) ---
  #pragma unroll 1
  for (int tp = 0; tp < nT; tp += 2) {
    phase(sA0, sA1, sB0, sB1, tp);
    phase(sB0, sB1, sA0, sA1, tp + 1);
  }

  // --- epilogue: l reduce (partner lane l^32 shares the q-row) ---
  float l_run = l_part + __shfl_xor(l_part, 32, 64);
  const float inv = 1.0f / l_run;
  float* orow = O + ((size_t)bh * Ss + qi) * Dd;
  #pragma unroll
  for (int dt = 0; dt < 4; ++dt) {
    #pragma unroll
    for (int r32 = 0; r32 < 4; ++r32) {
      float4 o4;
      o4.x = oacc[dt][4 * r32 + 0] * inv;
      o4.y = oacc[dt][4 * r32 + 1] * inv;
      o4.z = oacc[dt][4 * r32 + 2] * inv;
      o4.w = oacc[dt][4 * r32 + 3] * inv;
      *(float4*)(orow + dt * 32 + 8 * r32 + 4 * h) = o4;
    }
  }
}

// ---------------- fallback (round-2 self-contained kernel) if d_ws is too small ----------------
__device__ __forceinline__ int swzPf(int row, int col) { return row * 64 + (col ^ ((row & 7) << 3)); }

__global__ __launch_bounds__(256) void attn_fb(
    const float* __restrict__ Q, const float* __restrict__ K,
    const float* __restrict__ V, const int* __restrict__ MSK,
    float* __restrict__ O)
{
  __shared__ u16 Kls[KVBLK * Dd];
  __shared__ u16 Vts[Dd * KVBLK];
  __shared__ u16 Pls[4][16 * KVBLK];
  __shared__ int sAff;

  const int tid = threadIdx.x, lane = tid & 63, wid = tid >> 6;
  const int l15 = lane & 15, lg = lane >> 4;
  const int qt = blockIdx.x, bh = blockIdx.y, b = bh >> 4;
  const int qbase = qt * 64;
  const float scale = 0.08838834764831845f;

  const int qrowA = qbase + wid * 16 + l15;
  const float* qg = Q + ((size_t)bh * Ss + qrowA) * Dd + lg * 8;
  short8 qf[4];
  #pragma unroll
  for (int kc = 0; kc < 4; ++kc) {
    float4 x0 = *(const float4*)(qg + kc * 32);
    float4 x1 = *(const float4*)(qg + kc * 32 + 4);
    union { short8 v; u16 h[8]; } u;
    u.h[0] = f2bf(x0.x * scale); u.h[1] = f2bf(x0.y * scale);
    u.h[2] = f2bf(x0.z * scale); u.h[3] = f2bf(x0.w * scale);
    u.h[4] = f2bf(x1.x * scale); u.h[5] = f2bf(x1.y * scale);
    u.h[6] = f2bf(x1.z * scale); u.h[7] = f2bf(x1.w * scale);
    qf[kc] = u.v;
  }

  float m_run[4], l_run[4];
  floatx4 oacc[8];
  const floatx4 vzero = {0.f, 0.f, 0.f, 0.f};
  #pragma unroll
  for (int r = 0; r < 4; ++r) { m_run[r] = -3.0e38f; l_run[r] = 0.0f; }
  #pragma unroll
  for (int dt = 0; dt < 8; ++dt) oacc[dt] = vzero;
  const int qi0 = qbase + wid * 16 + lg * 4;

  for (int t = 0; t < NT; ++t) {
    if (t > blockIdx.x && !sAff) break;
    const int kvbase = t * KVBLK;
    const float* kg = K + ((size_t)bh * Ss + kvbase) * Dd;
    const float* vg = V + ((size_t)bh * Ss + kvbase) * Dd;
    #pragma unroll
    for (int it = 0; it < 8; ++it) {
      int e = (tid + it * 256) * 4;
      int r0 = e >> 7, c0 = e & 127;
      float4 x = *(const float4*)(kg + e);
      uint2 hk;
      hk.x = (u32)f2bf(x.x) | ((u32)f2bf(x.y) << 16);
      hk.y = (u32)f2bf(x.z) | ((u32)f2bf(x.w) << 16);
      *(uint2*)&Kls[swzK(r0, c0)] = hk;
      float4 y = *(const float4*)(vg + e);
      u16 hv[4] = { f2bf(y.x), f2bf(y.y), f2bf(y.z), f2bf(y.w) };
      #pragma unroll
      for (int j = 0; j < 4; ++j) Vts[swzV(c0 + j, r0)] = hv[j];
    }
    __syncthreads();

    float madd[4];
    #pragma unroll
    for (int kt = 0; kt < 4; ++kt)
      madd[kt] = MSK[b * Ss + kvbase + kt * 16 + l15] ? 0.0f : NEGF;

    floatx4 sacc[4];
    #pragma unroll
    for (int kt = 0; kt < 4; ++kt) sacc[kt] = vzero;
    #pragma unroll
    for (int kt = 0; kt < 4; ++kt) {
      const int krow = kt * 16 + l15;
      #pragma unroll
      for (int kc = 0; kc < 4; ++kc) {
        short8 kf = *(const short8*)&Kls[swzK(krow, kc * 32 + lg * 8)];
        sacc[kt] = __builtin_amdgcn_mfma_f32_16x16x32_bf16(qf[kc], kf, sacc[kt], 0, 0, 0);
      }
    }

    float mnew[4];
    #pragma unroll
    for (int r = 0; r < 4; ++r) mnew[r] = m_run[r];
    #pragma unroll
    for (int kt = 0; kt < 4; ++kt) {
      const int kvj = kvbase + kt * 16 + l15;
      #pragma unroll
      for (int r = 0; r < 4; ++r) {
        float s = sacc[kt][r] + madd[kt];
        if (kvj > qi0 + r) s += NEGF;
        sacc[kt][r] = s;
        mnew[r] = fmaxf(mnew[r], s);
      }
    }
    #pragma unroll
    for (int off = 1; off < 16; off <<= 1) {
      #pragma unroll
      for (int r = 0; r < 4; ++r)
        mnew[r] = fmaxf(mnew[r], __shfl_xor(mnew[r], off, 64));
    }
    float alpha[4], psum[4];
    #pragma unroll
    for (int r = 0; r < 4; ++r) {
      alpha[r] = __expf(m_run[r] - mnew[r]);
      m_run[r] = mnew[r];
      psum[r] = 0.f;
    }
    #pragma unroll
    for (int kt = 0; kt < 4; ++kt) {
      #pragma unroll
      for (int r = 0; r < 4; ++r) {
        float p = __expf(sacc[kt][r] - mnew[r]);
        psum[r] += p;
        Pls[wid][swzPf(lg * 4 + r, kt * 16 + l15)] = f2bf(p);
      }
    }
    #pragma unroll
    for (int off = 1; off < 16; off <<= 1) {
      #pragma unroll
      for (int r = 0; r < 4; ++r)
        psum[r] += __shfl_xor(psum[r], off, 64);
    }
    #pragma unroll
    for (int r = 0; r < 4; ++r) l_run[r] = l_run[r] * alpha[r] + psum[r];
    #pragma unroll
    for (int dt = 0; dt < 8; ++dt) {
      #pragma unroll
      for (int r = 0; r < 4; ++r) oacc[dt][r] *= alpha[r];
    }
    #pragma unroll
    for (int kc = 0; kc < 2; ++kc) {
      short8 pfr = *(const short8*)&Pls[wid][swzPf(l15, kc * 32 + lg * 8)];
      #pragma unroll
      for (int dt = 0; dt < 8; ++dt) {
        short8 vf = *(const short8*)&Vts[swzV(dt * 16 + l15, kc * 32 + lg * 8)];
        oacc[dt] = __builtin_amdgcn_mfma_f32_16x16x32_bf16(pfr, vf, oacc[dt], 0, 0, 0);
      }
    }
    __syncthreads();

    if (t == blockIdx.x) {
      if (tid == 0) sAff = 0;
      __syncthreads();
      bool aff = (m_run[0] < -5.0e8f) || (m_run[1] < -5.0e8f) ||
                 (m_run[2] < -5.0e8f) || (m_run[3] < -5.0e8f);
      if (aff) sAff = 1;
      __syncthreads();
    }
  }

  #pragma unroll
  for (int r = 0; r < 4; ++r) {
    float inv = 1.0f / l_run[r];
    float* op = O + ((size_t)bh * Ss + qi0 + r) * Dd + l15;
    #pragma unroll
    for (int dt = 0; dt < 8; ++dt) op[dt * 16] = oacc[dt][r] * inv;
  }
}

extern "C" void kernel_launch(void* const* d_in, const int* in_sizes, int n_in,
                              void* d_out, int out_size, void* d_ws, size_t ws_size,
                              hipStream_t stream) {
  const float* q = (const float*)d_in[0];
  const float* k = (const float*)d_in[1];
  const float* v = (const float*)d_in[2];
  const int* mask = (const int*)d_in[3];
  float* out = (float*)d_out;

  const size_t need = (size_t)2 * NELEM * sizeof(u16)           // Kp + Vp
                    + (size_t)MASKN * sizeof(float)             // Mg
                    + (size_t)64 * NT * 128 * sizeof(float)     // Sp (1 MB)
                    + 8 * sizeof(int);                          // F1M1
  if (ws_size >= need) {
    u16* Kp = (u16*)d_ws;
    u16* Vp = Kp + NELEM;
    float* Mg = (float*)(Vp + NELEM);
    float* Sp = Mg + MASKN;
    int* F1M1 = (int*)(Sp + (size_t)64 * NT * 128);
    prep_kv<<<dim3(64 * NT), 256, 0, stream>>>(k, v, mask, Kp, Vp, Mg, Sp);
    mask_scan<<<dim3(4), 256, 0, stream>>>(mask, F1M1);
    attn_fwd<<<dim3(1024), 256, 0, stream>>>(q, Kp, Vp, Mg, out);
    fixup<<<dim3(64), 128, 0, stream>>>(v, Sp, F1M1, out);
  } else {
    attn_fb<<<dim3(NT, 64), 256, 0, stream>>>(q, k, v, mask, out);
  }
}

// Round 20
// 163.570 us; speedup vs baseline: 1.2490x; 1.2490x over previous
//
#include <hip/hip_runtime.h>

typedef unsigned short u16;
typedef unsigned int   u32;
typedef __attribute__((ext_vector_type(8)))  short short8;   // 8 x bf16
typedef __attribute__((ext_vector_type(4)))  float floatx4;
typedef __attribute__((ext_vector_type(16))) float floatx16;

#define CNEG  (-1.4426950408889634e9f)   // -1e9 * log2(e)  (exp2 domain)
#define QSCL  (0.12753129020334545f)     // (1/sqrt(128)) * log2(e)
#define NEGF  (-1000000000.0f)           // fallback kernel (exp domain)
#define DEFER_THR 8.0f

__device__ __forceinline__ u16 f2bf(float x) {            // f32 -> bf16 RNE
  u32 u = __builtin_bit_cast(u32, x);
  u += 0x7fffu + ((u >> 16) & 1u);
  return (u16)(u >> 16);
}
__device__ __forceinline__ u32 cvtpk(float lo, float hi) { // 2xf32 -> packed bf16
  u32 r;
  asm("v_cvt_pk_bf16_f32 %0, %1, %2" : "=v"(r) : "v"(lo), "v"(hi));
  return r;
}

// fallback-kernel swizzles
__device__ __forceinline__ int swzK(int r, int c)  { return r * 128 + (c ^ ((r & 7) << 3)); }
__device__ __forceinline__ int svb(int d)          { return ((d & 7) ^ ((d >> 2) & 7)) << 3; }
__device__ __forceinline__ int swzV(int d, int kv) { return d * 64 + (kv ^ svb(d)); }
// swap bits 2<->3 of a 5-bit index (sigma for 32x32 C/D -> PV-B alignment)
__device__ __forceinline__ int swap23(int x) {
  return (x & ~0xC) | ((x & 4) << 1) | ((x & 8) >> 1);
}

__device__ __forceinline__ void gld16(const void* g, void* l) {
  __builtin_amdgcn_global_load_lds(
      (const __attribute__((address_space(1))) u32*)g,
      (__attribute__((address_space(3))) u32*)l, 16, 0, 0);
}

constexpr int Hh = 16, Ss = 2048, Dd = 128;
constexpr int KVBLK = 64;
constexpr int NT = Ss / KVBLK;            // 32 kv tiles
constexpr int TILE = KVBLK * Dd;          // 8192 elements = 16 KB per bf16 tile
constexpr int NELEM = 4 * Hh * Ss * Dd;   // 16777216 per tensor
constexpr int MASKN = 4 * Ss;             // 8192 mask entries

// ---------------- prep: K/V -> bf16 fragment-linear (32x32); mask -> CNEG-adds; masked-V partials ----------------
__global__ __launch_bounds__(256) void prep_kv(const float* __restrict__ K,
                                               const float* __restrict__ V,
                                               const int* __restrict__ MSK,
                                               u16* __restrict__ Kp, u16* __restrict__ Vp,
                                               float* __restrict__ Mg,
                                               float* __restrict__ Sp) {
  __shared__ u16 Vl[KVBLK * 132];
  const int blk = blockIdx.x, tid = threadIdx.x;   // blk = bh*32 + t
  const float* kg = K + (size_t)blk * TILE;
  const float* vg = V + (size_t)blk * TILE;
  u16* kp = Kp + (size_t)blk * TILE;
  u16* vp = Vp + (size_t)blk * TILE;

  if (blk < MASKN / 256) {                         // mask -> exp2-domain additive floats
    int i = blk * 256 + tid;
    Mg[i] = MSK[i] ? 0.0f : CNEG;
  }

  // K fragments: frag f = kvb*8+s; lane ln holds Kslot[kvb*32+(ln&31)][s*16+(ln>>5)*8+i],
  // slot row -> source kv = kvb*32 + swap23(ln&31)
  #pragma unroll
  for (int it = 0; it < 4; ++it) {
    int ch = tid + it * 256;             // chunk = f*64 + ln, 0..1023
    int f = ch >> 6, ln = ch & 63;
    int kvb = f >> 3, s = f & 7;
    int kvs = kvb * 32 + swap23(ln & 31);          // source kv row
    int d0 = s * 16 + (ln >> 5) * 8;
    const float* src = kg + kvs * 128 + d0;
    float4 a = *(const float4*)src, bq = *(const float4*)(src + 4);
    union { short8 v; u16 h[8]; } u;
    u.h[0] = f2bf(a.x);  u.h[1] = f2bf(a.y);  u.h[2] = f2bf(a.z);  u.h[3] = f2bf(a.w);
    u.h[4] = f2bf(bq.x); u.h[5] = f2bf(bq.y); u.h[6] = f2bf(bq.z); u.h[7] = f2bf(bq.w);
    *(short8*)(kp + ch * 8) = u.v;
  }
  // V: coalesced read -> LDS bf16 [kv][d]
  #pragma unroll
  for (int it = 0; it < 8; ++it) {
    int e = (tid + it * 256) * 4;
    int r = e >> 7, c = e & 127;
    float4 a = *(const float4*)(vg + e);
    uint2 w;
    w.x = (u32)f2bf(a.x) | ((u32)f2bf(a.y) << 16);
    w.y = (u32)f2bf(a.z) | ((u32)f2bf(a.w) << 16);
    *(uint2*)&Vl[r * 132 + c] = w;
  }
  __syncthreads();
  // V fragments: frag f = dt*4+s; lane ln holds V^T[dt*32+(ln&31)][s*16+(ln>>5)*8+i]
  #pragma unroll
  for (int it = 0; it < 4; ++it) {
    int ch = tid + it * 256;
    int f = ch >> 6, ln = ch & 63;
    int dt = f >> 2, s = f & 3;
    int d = dt * 32 + (ln & 31);
    int kv0 = s * 16 + (ln >> 5) * 8;
    union { short8 v; u16 h[8]; } u;
    #pragma unroll
    for (int i = 0; i < 8; ++i) u.h[i] = Vl[(kv0 + i) * 132 + d];
    *(short8*)(vp + ch * 8) = u.v;
  }

  // masked V column partial sums (f32, for the quirk fixup)
  {
    const int d = tid & 127, hf = tid >> 7;
    const int bb = blk >> 9;
    const int j0 = (blk & 31) * 64 + hf * 32;
    float acc = 0.0f;
    #pragma unroll 4
    for (int jj = 0; jj < 32; ++jj) {
      const float mfv = MSK[bb * Ss + j0 + jj] ? 1.0f : 0.0f;
      acc = fmaf(mfv, vg[(hf * 32 + jj) * 128 + d], acc);
    }
    __syncthreads();
    float* sred = (float*)Vl;
    if (hf) sred[d] = acc;
    __syncthreads();
    if (!hf) Sp[(size_t)blk * 128 + d] = acc + sred[d];
  }
}

// ---------------- F1[b] = first unmasked index (Ss if none); M1[b] = #unmasked ----------------
__global__ __launch_bounds__(256) void mask_scan(const int* __restrict__ MSK,
                                                 int* __restrict__ F1M1) {
  __shared__ int sf[4], sc[4];
  const int b = blockIdx.x, tid = threadIdx.x, lane = tid & 63, wid = tid >> 6;
  int first = Ss, cnt = 0;
  for (int j = tid; j < Ss; j += 256)
    if (MSK[b * Ss + j]) { if (j < first) first = j; cnt++; }
  #pragma unroll
  for (int off = 1; off < 64; off <<= 1) {
    first = min(first, __shfl_xor(first, off, 64));
    cnt  += __shfl_xor(cnt, off, 64);
  }
  if (lane == 0) { sf[wid] = first; sc[wid] = cnt; }
  __syncthreads();
  if (tid == 0) {
    int f = min(min(sf[0], sf[1]), min(sf[2], sf[3]));
    int c = sc[0] + sc[1] + sc[2] + sc[3];
    F1M1[b] = f; F1M1[4 + b] = c;
  }
}

// ---------------- fixup for quirk rows (all-masked visible prefix): uniform average ----------------
__global__ __launch_bounds__(128) void fixup(const float* __restrict__ V,
                                             const float* __restrict__ Sp,
                                             const int* __restrict__ F1M1,
                                             float* __restrict__ O) {
  const int bh = blockIdx.x, b = bh >> 4, d = threadIdx.x;
  const int f1 = F1M1[b];
  if (f1 == 0) return;
  const int m1 = F1M1[4 + b];
  float s1v = 0.0f;
  #pragma unroll
  for (int t = 0; t < NT; ++t) s1v += Sp[((size_t)bh * NT + t) * 128 + d];
  float pref = 0.0f;
  for (int i = 0; i < f1; ++i) {
    pref += V[((size_t)bh * Ss + i) * Dd + d];
    O[((size_t)bh * Ss + i) * Dd + d] = (pref + s1v) / (float)(i + 1 + m1);
  }
}

// ---------------- main: 4 waves x 32 q-rows, K+V double-buffered, prefetch NEVER drained mid-tile ----------------
// vmcnt is FIFO: mask loads issued BEFORE the stage() prefetch, so consuming them waits only
// vmcnt(8) and the prefetch stays in flight until the end-of-tile barrier.
__global__ __launch_bounds__(256, 2) void attn_fwd(const float* __restrict__ Q,
                                                   const u16* __restrict__ Kp,
                                                   const u16* __restrict__ Vp,
                                                   const float* __restrict__ Mg,
                                                   float* __restrict__ O) {
  __shared__ u16 Kl[2][TILE];              // 32 KB (double-buffered)
  __shared__ u16 Vt[2][TILE];              // 32 KB (double-buffered)

  const int tid = threadIdx.x, lane = tid & 63, wid = tid >> 6;
  const int l31 = lane & 31, h = lane >> 5;
  const int id = blockIdx.x;                       // 512 blocks, bijective XCD swizzle
  const int wg = (id & 7) * 64 + (id >> 3);
  const int bh = wg >> 3, pr = wg & 7, b = bh >> 4;

  const size_t tb = (size_t)bh * NT;
  auto stage = [&](int buf, int t) {       // 16KB K + 16KB V with 256 threads: 4+4 gld16/thread
    const char* gk = (const char*)(Kp + (tb + t) * TILE) + wid * 1024 + lane * 16;
    const char* gv = (const char*)(Vp + (tb + t) * TILE) + wid * 1024 + lane * 16;
    char* lk = (char*)&Kl[buf][0] + wid * 1024;    // wave-uniform dest base
    char* lv = (char*)&Vt[buf][0] + wid * 1024;
    #pragma unroll
    for (int i = 0; i < 4; ++i) {                  // 4 x 4096B = 16KB per tensor
      gld16(gk + i * 4096, lk + i * 4096);
      gld16(gv + i * 4096, lv + i * 4096);
    }
  };

  stage(0, 0);
  __syncthreads();
  int cur = 0;

  #pragma unroll 1
  for (int strip = 0; strip < 2; ++strip) {
    const int qt = strip ? (15 - pr) : pr;
    const int qbase = qt * 128;
    const int nT = 2 * qt + 2;                     // causal kv tiles for this strip
    const int qi = qbase + wid * 32 + l31;         // this lane's single q-row

    // Q fragments (B operand): col=q=l31, d = s*16 + h*8 + i
    const float* qg = Q + ((size_t)bh * Ss + qi) * Dd + h * 8;
    short8 qf[8];
    #pragma unroll
    for (int s = 0; s < 8; ++s) {
      float4 x0 = *(const float4*)(qg + s * 16);
      float4 x1 = *(const float4*)(qg + s * 16 + 4);
      union { short8 v; u16 hh[8]; } u;
      u.hh[0] = f2bf(x0.x * QSCL); u.hh[1] = f2bf(x0.y * QSCL);
      u.hh[2] = f2bf(x0.z * QSCL); u.hh[3] = f2bf(x0.w * QSCL);
      u.hh[4] = f2bf(x1.x * QSCL); u.hh[5] = f2bf(x1.y * QSCL);
      u.hh[6] = f2bf(x1.z * QSCL); u.hh[7] = f2bf(x1.w * QSCL);
      qf[s] = u.v;
    }

    float m_run = -3.0e38f, l_part = 0.0f;
    floatx16 oacc[4];
    #pragma unroll
    for (int dt = 0; dt < 4; ++dt)
      #pragma unroll
      for (int r = 0; r < 16; ++r) oacc[dt][r] = 0.0f;

    #pragma unroll 1
    for (int t = 0; t < nT; ++t) {
      const int kvbase = t * KVBLK;

      // --- mask loads FIRST: oldest in the VMEM FIFO, so consuming them waits
      //     only vmcnt(8) and leaves the stage() prefetch in flight ---
      const float* mrow = Mg + b * Ss + kvbase + h * 8;
      float4 a0 = *(const float4*)(mrow);
      float4 a1 = *(const float4*)(mrow + 4);
      float4 a2 = *(const float4*)(mrow + 16);
      float4 a3 = *(const float4*)(mrow + 20);
      float4 a4 = *(const float4*)(mrow + 32);
      float4 a5 = *(const float4*)(mrow + 36);
      float4 a6 = *(const float4*)(mrow + 48);
      float4 a7 = *(const float4*)(mrow + 52);

      // --- prefetch next tile (or strip1's tile 0); lands before the end-of-tile barrier ---
      const int nxt = (t + 1 < nT) ? (t + 1) : (strip == 0 ? 0 : -1);
      if (nxt >= 0) stage(cur ^ 1, nxt);

      // --- C-init = mask adds (+ causal on diagonal) ---
      // score slot (kvb, reg r) -> kv j = kvbase + kvb*32 + (r>>3)*16 + h*8 + (r&7)
      floatx16 s0, s1;
      s0[0]=a0.x;  s0[1]=a0.y;  s0[2]=a0.z;  s0[3]=a0.w;
      s0[4]=a1.x;  s0[5]=a1.y;  s0[6]=a1.z;  s0[7]=a1.w;
      s0[8]=a2.x;  s0[9]=a2.y;  s0[10]=a2.z; s0[11]=a2.w;
      s0[12]=a3.x; s0[13]=a3.y; s0[14]=a3.z; s0[15]=a3.w;
      s1[0]=a4.x;  s1[1]=a4.y;  s1[2]=a4.z;  s1[3]=a4.w;
      s1[8]=a6.x;  s1[9]=a6.y;  s1[10]=a6.z; s1[11]=a6.w;
      s1[4]=a5.x;  s1[5]=a5.y;  s1[6]=a5.z;  s1[7]=a5.w;
      s1[12]=a7.x; s1[13]=a7.y; s1[14]=a7.z; s1[15]=a7.w;
      if (kvbase + KVBLK - 1 >= qbase + wid * 32) {     // wave-uniform: diagonal tiles
        #pragma unroll
        for (int r = 0; r < 16; ++r) {
          const int j0 = kvbase + ((r >> 3) << 4) + h * 8 + (r & 7);
          if (j0 > qi)      s0[r] += CNEG;
          if (j0 + 32 > qi) s1[r] += CNEG;
        }
      }

      // --- S^T = K.Q^T (C-in = masks); fragment-linear K (resident buffer) ---
      const u16* kb = &Kl[cur][lane * 8];
      __builtin_amdgcn_s_setprio(1);
      #pragma unroll
      for (int s = 0; s < 8; ++s) {
        short8 k0 = *(const short8*)&kb[s * 512];
        short8 k1 = *(const short8*)&kb[(8 + s) * 512];
        s0 = __builtin_amdgcn_mfma_f32_32x32x16_bf16(k0, qf[s], s0, 0, 0, 0);
        s1 = __builtin_amdgcn_mfma_f32_32x32x16_bf16(k1, qf[s], s1, 0, 0, 0);
      }
      __builtin_amdgcn_s_setprio(0);

      // --- softmax: local tree max, defer-max common path has no cross-lane ops ---
      float mx8[8];
      #pragma unroll
      for (int r = 0; r < 8; ++r)
        mx8[r] = fmaxf(fmaxf(s0[r], s0[r + 8]), fmaxf(s1[r], s1[r + 8]));
      float mx4[4];
      #pragma unroll
      for (int r = 0; r < 4; ++r) mx4[r] = fmaxf(mx8[r], mx8[r + 4]);
      float pmax = fmaxf(fmaxf(mx4[0], mx4[1]), fmaxf(mx4[2], mx4[3]));

      float mn = m_run;
      if (!__all(pmax <= m_run + DEFER_THR)) {
        pmax = fmaxf(pmax, __shfl_xor(pmax, 32, 64));
        mn = fmaxf(m_run, pmax);
        const float alpha = exp2f(m_run - mn);
        m_run = mn;
        l_part *= alpha;
        #pragma unroll
        for (int dt = 0; dt < 4; ++dt)
          #pragma unroll
          for (int r = 0; r < 16; ++r) oacc[dt][r] *= alpha;
      }
      #pragma unroll
      for (int r = 0; r < 16; ++r) {
        s0[r] = exp2f(s0[r] - mn);
        s1[r] = exp2f(s1[r] - mn);
      }

      // --- P fragments: sigma packs sacc regs DIRECTLY into PV B-operand order ---
      union { short8 v; u32 w[4]; } pu[4];
      #pragma unroll
      for (int j = 0; j < 4; ++j) {
        pu[0].w[j] = cvtpk(s0[2 * j],     s0[2 * j + 1]);
        pu[1].w[j] = cvtpk(s0[8 + 2 * j], s0[8 + 2 * j + 1]);
        pu[2].w[j] = cvtpk(s1[2 * j],     s1[2 * j + 1]);
        pu[3].w[j] = cvtpk(s1[8 + 2 * j], s1[8 + 2 * j + 1]);
      }

      // --- O^T += V^T.P^T ; fragment-linear V (resident buffer) ---
      const u16* vb = &Vt[cur][lane * 8];
      __builtin_amdgcn_s_setprio(1);
      #pragma unroll
      for (int ss = 0; ss < 4; ++ss) {
        #pragma unroll
        for (int dt = 0; dt < 4; ++dt) {
          short8 vf = *(const short8*)&vb[(dt * 4 + ss) * 512];
          oacc[dt] = __builtin_amdgcn_mfma_f32_32x32x16_bf16(vf, pu[ss].v, oacc[dt], 0, 0, 0);
        }
      }
      __builtin_amdgcn_s_setprio(0);

      // --- l update via balanced tree (overlaps PV MFMAs) ---
      {
        float t8[8];
        #pragma unroll
        for (int r = 0; r < 8; ++r)
          t8[r] = (s0[r] + s0[r + 8]) + (s1[r] + s1[r + 8]);
        float t4a = t8[0] + t8[4], t4b = t8[1] + t8[5];
        float t4c = t8[2] + t8[6], t4d = t8[3] + t8[7];
        l_part += (t4a + t4b) + (t4c + t4d);
      }

      __syncthreads();                     // next tile staged + buffer reads done
      cur ^= 1;
    }

    // --- strip epilogue: l reduce (partner lane l^32 shares the q-row) ---
    float l_run = l_part + __shfl_xor(l_part, 32, 64);
    const float inv = 1.0f / l_run;
    float* orow = O + ((size_t)bh * Ss + qi) * Dd;
    #pragma unroll
    for (int dt = 0; dt < 4; ++dt) {
      #pragma unroll
      for (int r32 = 0; r32 < 4; ++r32) {
        float4 o4;
        o4.x = oacc[dt][4 * r32 + 0] * inv;
        o4.y = oacc[dt][4 * r32 + 1] * inv;
        o4.z = oacc[dt][4 * r32 + 2] * inv;
        o4.w = oacc[dt][4 * r32 + 3] * inv;
        *(float4*)(orow + dt * 32 + 8 * r32 + 4 * h) = o4;
      }
    }
  }
}

// ---------------- fallback (round-2 self-contained kernel) if d_ws is too small ----------------
__device__ __forceinline__ int swzPf(int row, int col) { return row * 64 + (col ^ ((row & 7) << 3)); }

__global__ __launch_bounds__(256) void attn_fb(
    const float* __restrict__ Q, const float* __restrict__ K,
    const float* __restrict__ V, const int* __restrict__ MSK,
    float* __restrict__ O)
{
  __shared__ u16 Kls[KVBLK * Dd];
  __shared__ u16 Vts[Dd * KVBLK];
  __shared__ u16 Pls[4][16 * KVBLK];
  __shared__ int sAff;

  const int tid = threadIdx.x, lane = tid & 63, wid = tid >> 6;
  const int l15 = lane & 15, lg = lane >> 4;
  const int qt = blockIdx.x, bh = blockIdx.y, b = bh >> 4;
  const int qbase = qt * 64;
  const float scale = 0.08838834764831845f;

  const int qrowA = qbase + wid * 16 + l15;
  const float* qg = Q + ((size_t)bh * Ss + qrowA) * Dd + lg * 8;
  short8 qf[4];
  #pragma unroll
  for (int kc = 0; kc < 4; ++kc) {
    float4 x0 = *(const float4*)(qg + kc * 32);
    float4 x1 = *(const float4*)(qg + kc * 32 + 4);
    union { short8 v; u16 h[8]; } u;
    u.h[0] = f2bf(x0.x * scale); u.h[1] = f2bf(x0.y * scale);
    u.h[2] = f2bf(x0.z * scale); u.h[3] = f2bf(x0.w * scale);
    u.h[4] = f2bf(x1.x * scale); u.h[5] = f2bf(x1.y * scale);
    u.h[6] = f2bf(x1.z * scale); u.h[7] = f2bf(x1.w * scale);
    qf[kc] = u.v;
  }

  float m_run[4], l_run[4];
  floatx4 oacc[8];
  const floatx4 vzero = {0.f, 0.f, 0.f, 0.f};
  #pragma unroll
  for (int r = 0; r < 4; ++r) { m_run[r] = -3.0e38f; l_run[r] = 0.0f; }
  #pragma unroll
  for (int dt = 0; dt < 8; ++dt) oacc[dt] = vzero;
  const int qi0 = qbase + wid * 16 + lg * 4;

  for (int t = 0; t < NT; ++t) {
    if (t > blockIdx.x && !sAff) break;
    const int kvbase = t * KVBLK;
    const float* kg = K + ((size_t)bh * Ss + kvbase) * Dd;
    const float* vg = V + ((size_t)bh * Ss + kvbase) * Dd;
    #pragma unroll
    for (int it = 0; it < 8; ++it) {
      int e = (tid + it * 256) * 4;
      int r0 = e >> 7, c0 = e & 127;
      float4 x = *(const float4*)(kg + e);
      uint2 hk;
      hk.x = (u32)f2bf(x.x) | ((u32)f2bf(x.y) << 16);
      hk.y = (u32)f2bf(x.z) | ((u32)f2bf(x.w) << 16);
      *(uint2*)&Kls[swzK(r0, c0)] = hk;
      float4 y = *(const float4*)(vg + e);
      u16 hv[4] = { f2bf(y.x), f2bf(y.y), f2bf(y.z), f2bf(y.w) };
      #pragma unroll
      for (int j = 0; j < 4; ++j) Vts[swzV(c0 + j, r0)] = hv[j];
    }
    __syncthreads();

    float madd[4];
    #pragma unroll
    for (int kt = 0; kt < 4; ++kt)
      madd[kt] = MSK[b * Ss + kvbase + kt * 16 + l15] ? 0.0f : NEGF;

    floatx4 sacc[4];
    #pragma unroll
    for (int kt = 0; kt < 4; ++kt) sacc[kt] = vzero;
    #pragma unroll
    for (int kt = 0; kt < 4; ++kt) {
      const int krow = kt * 16 + l15;
      #pragma unroll
      for (int kc = 0; kc < 4; ++kc) {
        short8 kf = *(const short8*)&Kls[swzK(krow, kc * 32 + lg * 8)];
        sacc[kt] = __builtin_amdgcn_mfma_f32_16x16x32_bf16(qf[kc], kf, sacc[kt], 0, 0, 0);
      }
    }

    float mnew[4];
    #pragma unroll
    for (int r = 0; r < 4; ++r) mnew[r] = m_run[r];
    #pragma unroll
    for (int kt = 0; kt < 4; ++kt) {
      const int kvj = kvbase + kt * 16 + l15;
      #pragma unroll
      for (int r = 0; r < 4; ++r) {
        float s = sacc[kt][r] + madd[kt];
        if (kvj > qi0 + r) s += NEGF;
        sacc[kt][r] = s;
        mnew[r] = fmaxf(mnew[r], s);
      }
    }
    #pragma unroll
    for (int off = 1; off < 16; off <<= 1) {
      #pragma unroll
      for (int r = 0; r < 4; ++r)
        mnew[r] = fmaxf(mnew[r], __shfl_xor(mnew[r], off, 64));
    }
    float alpha[4], psum[4];
    #pragma unroll
    for (int r = 0; r < 4; ++r) {
      alpha[r] = __expf(m_run[r] - mnew[r]);
      m_run[r] = mnew[r];
      psum[r] = 0.f;
    }
    #pragma unroll
    for (int kt = 0; kt < 4; ++kt) {
      #pragma unroll
      for (int r = 0; r < 4; ++r) {
        float p = __expf(sacc[kt][r] - mnew[r]);
        psum[r] += p;
        Pls[wid][swzPf(lg * 4 + r, kt * 16 + l15)] = f2bf(p);
      }
    }
    #pragma unroll
    for (int off = 1; off < 16; off <<= 1) {
      #pragma unroll
      for (int r = 0; r < 4; ++r)
        psum[r] += __shfl_xor(psum[r], off, 64);
    }
    #pragma unroll
    for (int r = 0; r < 4; ++r) l_run[r] = l_run[r] * alpha[r] + psum[r];
    #pragma unroll
    for (int dt = 0; dt < 8; ++dt) {
      #pragma unroll
      for (int r = 0; r < 4; ++r) oacc[dt][r] *= alpha[r];
    }
    #pragma unroll
    for (int kc = 0; kc < 2; ++kc) {
      short8 pfr = *(const short8*)&Pls[wid][swzPf(l15, kc * 32 + lg * 8)];
      #pragma unroll
      for (int dt = 0; dt < 8; ++dt) {
        short8 vf = *(const short8*)&Vts[swzV(dt * 16 + l15, kc * 32 + lg * 8)];
        oacc[dt] = __builtin_amdgcn_mfma_f32_16x16x32_bf16(pfr, vf, oacc[dt], 0, 0, 0);
      }
    }
    __syncthreads();

    if (t == blockIdx.x) {
      if (tid == 0) sAff = 0;
      __syncthreads();
      bool aff = (m_run[0] < -5.0e8f) || (m_run[1] < -5.0e8f) ||
                 (m_run[2] < -5.0e8f) || (m_run[3] < -5.0e8f);
      if (aff) sAff = 1;
      __syncthreads();
    }
  }

  #pragma unroll
  for (int r = 0; r < 4; ++r) {
    float inv = 1.0f / l_run[r];
    float* op = O + ((size_t)bh * Ss + qi0 + r) * Dd + l15;
    #pragma unroll
    for (int dt = 0; dt < 8; ++dt) op[dt * 16] = oacc[dt][r] * inv;
  }
}

extern "C" void kernel_launch(void* const* d_in, const int* in_sizes, int n_in,
                              void* d_out, int out_size, void* d_ws, size_t ws_size,
                              hipStream_t stream) {
  const float* q = (const float*)d_in[0];
  const float* k = (const float*)d_in[1];
  const float* v = (const float*)d_in[2];
  const int* mask = (const int*)d_in[3];
  float* out = (float*)d_out;

  const size_t need = (size_t)2 * NELEM * sizeof(u16)           // Kp + Vp
                    + (size_t)MASKN * sizeof(float)             // Mg
                    + (size_t)64 * NT * 128 * sizeof(float)     // Sp (1 MB)
                    + 8 * sizeof(int);                          // F1M1
  if (ws_size >= need) {
    u16* Kp = (u16*)d_ws;
    u16* Vp = Kp + NELEM;
    float* Mg = (float*)(Vp + NELEM);
    float* Sp = Mg + MASKN;
    int* F1M1 = (int*)(Sp + (size_t)64 * NT * 128);
    prep_kv<<<dim3(64 * NT), 256, 0, stream>>>(k, v, mask, Kp, Vp, Mg, Sp);
    mask_scan<<<dim3(4), 256, 0, stream>>>(mask, F1M1);
    attn_fwd<<<dim3(512), 256, 0, stream>>>(q, Kp, Vp, Mg, out);
    fixup<<<dim3(64), 128, 0, stream>>>(v, Sp, F1M1, out);
  } else {
    attn_fb<<<dim3(NT, 64), 256, 0, stream>>>(q, k, v, mask, out);
  }
}